// Round 6
// baseline (435.788 us; speedup 1.0000x reference)
//
#include <hip/hip_runtime.h>

// YOLO post-process, ONE fused kernel (R10):
//  Each block scans one (img, 1600-anchor chunk) for exact top-64 (R9 body,
//  unchanged: float4 loads; fast conservative bound prod=(1+e^-o)(1+e^-c)
//  gating into a dense LDS worklist; exact OCML score_key on ~100-400
//  survivors; wave-register tournament for the final top-64).
//  Then: device-scope release fence + atomicAdd(ready[img]); the LAST of the
//  21 blocks per image (old==20, unique) acquires and runs merge+NMS inline
//  (R7 in-register run-merges + IoU bit-matrix + greedy sweep).
//  Rationale: merge_nms measured ~40-45us as a separate 128-block dispatch
//  (half the GPU idle, serialized after ALL scans). Tail-fusion overlaps it
//  with other images' scans and deletes a dispatch boundary.
//  Correctness (Guideline 16): __syncthreads drains block stores to L2;
//  t0 __threadfence (agent release, wbl2) before atomicAdd; tail block
//  __threadfence (acquire, inv) after observing count==20 -> all 21 runs
//  visible across XCDs. ready[] zeroed per launch via hipMemsetAsync.
//  Scan LDS (keys+wl) and merge LDS overlay in a union (~22.9KB, same
//  occupancy as R9: 6 blocks/CU).

#define NUM_CLASSES 5
#define CONF_THRESH 0.6f
#define NMS_THRESH  0.2f
#define TOPK   64
#define BATCH  128
#define TOTK   192
#define NCH    21      // per image: 16 (lvl0) + 4 (lvl1) + 1 (lvl2), 1600 anchors each
#define CHUNK  1600
#define SCAP   2048    // LDS candidate buffer (u64)
#define NTHR   320     // 5 waves; anchors: 4/thread vectorized + 1 tail
#define WCAP   1600    // worklist capacity (overflow -> exact fallback)

typedef unsigned long long u64;
typedef unsigned int u32;

// ---------------- shared helpers ----------------

// In-register bitonic sort of 64 u32 across one wave, descending by lane.
__device__ inline u32 wave_sort64_desc_u32(u32 v, int lane) {
  #pragma unroll
  for (int k = 2; k <= 64; k <<= 1) {
    #pragma unroll
    for (int j = k >> 1; j > 0; j >>= 1) {
      u32 o = __shfl_xor(v, j, 64);
      bool keepMax = (((lane & k) == 0) != ((lane & j) != 0));
      v = keepMax ? (v > o ? v : o) : (v < o ? v : o);
    }
  }
  return v;
}

// In-register bitonic sort of 64 u64 across one wave, descending by lane.
__device__ inline u64 wave_sort64_desc(u64 v, int lane) {
  #pragma unroll
  for (int k = 2; k <= 64; k <<= 1) {
    #pragma unroll
    for (int j = k >> 1; j > 0; j >>= 1) {
      u64 o = __shfl_xor(v, j, 64);
      bool keepMax = (((lane & k) == 0) != ((lane & j) != 0));
      v = keepMax ? (v > o ? v : o) : (v < o ? v : o);
    }
  }
  return v;
}

__device__ __forceinline__ u64 u64max(u64 a, u64 b) { return a > b ? a : b; }
__device__ __forceinline__ u64 u64min(u64 a, u64 b) { return a < b ? a : b; }

// Descending bitonic MERGE of a bitonic 64-seq held one elem/lane.
__device__ __forceinline__ u64 bmerge64_desc(u64 v, int lane) {
  #pragma unroll
  for (int j = 32; j > 0; j >>= 1) {
    u64 o = __shfl_xor(v, j, 64);
    v = ((lane & j) == 0) ? u64max(v, o) : u64min(v, o);
  }
  return v;
}

// a = A[lane] (A desc-sorted), brev = B[63-lane] (B desc-sorted).
// Lane-th element of the desc-sorted top-64 of A∪B.
__device__ __forceinline__ u64 merge_top64(u64 a, u64 brev, int lane) {
  return bmerge64_desc(u64max(a, brev), lane);
}

__device__ __forceinline__ u64 merge4_top64(u64 a, u64 brev, u64 c, u64 drev, int lane) {
  u64 ab = merge_top64(a, brev, lane);
  u64 cd = merge_top64(c, drev, lane);
  u64 cdr = __shfl(cd, 63 - lane, 64);
  return merge_top64(ab, cdr, lane);
}

// score = sqrt(sigmoid(obj)*sigmoid(cls)); key = (score_bits<<32) | ~idx
// reproduces lax.top_k order (value desc, index asc). Bit-exact vs numpy
// (absmax 0.0 R2-R9) -- do not alter the float expressions.
__device__ inline u64 score_key(float so, float cv, int idx) {
  float sc = 1.0f / (1.0f + expf(-cv));
  float s  = sqrtf(__fmul_rn(so, sc));
  return ((u64)__float_as_uint(s) << 32) | (u32)(~(u32)idx);
}

__device__ inline float sigmoidf(float x) { return 1.0f / (1.0f + expf(-x)); }

// ---------------- fused kernel ----------------

struct MergeLds {
  u64   lds_runs[256];
  u64   lvlkeys[TOTK];
  u64   skeys[TOTK];
  int   slb[TOTK];
  float sbx[TOTK * 4];
  float sX1[TOTK], sY1[TOTK], sX2[TOTK], sY2[TOTK], sA[TOTK];
  u64   rows[TOTK * 3];
};
struct ScanLds {
  u64 keys[SCAP];
  u32 wl[WCAP];
};
union SharedU {
  ScanLds  s;   // 22784 B
  MergeLds m;   // 17408 B
};

__global__ __launch_bounds__(NTHR) void yolo_fused(
    const float* __restrict__ obj8,  const float* __restrict__ cls8,
    const float* __restrict__ obj16, const float* __restrict__ cls16,
    const float* __restrict__ obj32, const float* __restrict__ cls32,
    const float* __restrict__ reg8,  const float* __restrict__ reg16,
    const float* __restrict__ reg32,
    u64* __restrict__ ws_part, int* __restrict__ ready,
    float* __restrict__ out) {
  __shared__ SharedU u;
  __shared__ int cnt;
  __shared__ int wcnt;
  __shared__ u32 sthr[5];
  __shared__ u64 svalid[3];
  __shared__ u64 skeep[3];
  __shared__ float lmarr[3];
  __shared__ int tailflag;

  const int bx  = blockIdx.x;
  const int img = bx / NCH;
  const int c   = bx - img * NCH;
  const int t   = threadIdx.x;
  const int lane = t & 63, wv = t >> 6;

  // ================= scan phase (R9 body, byte-identical math) =============
  {
    const float *obj, *cls;
    int hw, off;
    if (c < 16)      { obj = obj8;  cls = cls8;  hw = 25600; off = c * CHUNK; }
    else if (c < 20) { obj = obj16; cls = cls16; hw = 6400;  off = (c - 16) * CHUNK; }
    else             { obj = obj32; cls = cls32; hw = 1600;  off = 0; }
    obj += (size_t)img * hw + off;
    cls += ((size_t)img * hw + off) * NUM_CLASSES;

    // cheap bound pass: ff[k] = (1+e^-obj)(1+e^-cls) ~= 1/score^2
    // (monotone DECREASING in score; fast ops, rel err <= ~2^-21).
    // ff[] only indexed by compile-time constants -> stays in VGPRs (R4).
    float ff[25];
    {
      const float4* c4 = (const float4*)cls + (size_t)t * 5;
      float4 q0 = c4[0], q1 = c4[1], q2 = c4[2], q3 = c4[3], q4 = c4[4];
      float4 ov = ((const float4*)obj)[t];
      float cv[20] = { q0.x,q0.y,q0.z,q0.w, q1.x,q1.y,q1.z,q1.w,
                       q2.x,q2.y,q2.z,q2.w, q3.x,q3.y,q3.z,q3.w,
                       q4.x,q4.y,q4.z,q4.w };
      float dob[4] = { 1.0f + __expf(-ov.x), 1.0f + __expf(-ov.y),
                       1.0f + __expf(-ov.z), 1.0f + __expf(-ov.w) };
      #pragma unroll
      for (int a = 0; a < 4; ++a)
        #pragma unroll
        for (int j = 0; j < 5; ++j)
          ff[a * 5 + j] = dob[a] * (1.0f + __expf(-cv[a * 5 + j]));
      float ot = obj[1280 + t];
      float dot_ = 1.0f + __expf(-ot);
      #pragma unroll
      for (int j = 0; j < 5; ++j) {
        float cvt = cls[(1280 + t) * 5 + j];
        ff[20 + j] = dot_ * (1.0f + __expf(-cvt));
      }
    }

    // seed: per-wave 16th-smallest thread-min-prod (= 16th-largest fast
    // score). >=16 threads/wave have an entry whose TRUE score >= ts ->
    // >=80 exact keys chunk-wide pass the exact filter (>= 64 needed).
    float pmin = ff[0];
    #pragma unroll
    for (int i = 1; i < 25; ++i) pmin = fminf(pmin, ff[i]);
    u32 srt = wave_sort64_desc_u32(__float_as_uint(pmin), lane);
    if (lane == 48) sthr[wv] = srt;        // 16th smallest = 49th largest
    if (t == 0) { cnt = 0; wcnt = 0; }
    __syncthreads();
    u64 thr; float thr_inv;
    {
      float pmax = __uint_as_float(sthr[0]);
      pmax = fmaxf(pmax, __uint_as_float(sthr[1]));
      pmax = fmaxf(pmax, __uint_as_float(sthr[2]));
      pmax = fmaxf(pmax, __uint_as_float(sthr[3]));
      pmax = fmaxf(pmax, __uint_as_float(sthr[4]));
      float ts = sqrtf(__fdiv_rn(1.0f, pmax)) * (1.0f - 1e-4f);
      // key > thr  <=>  score_bits >= bits(ts)  <=>  score >= ts
      thr = ((u64)__float_as_uint(ts) << 32) - 1ull;
      // gate: prod <= thr_inv  <==  score >= ts (2e-4 conservative slack)
      thr_inv = __fdiv_rn(1.0f, __fmul_rn(__fmul_rn(ts, ts), 1.0f - 2e-4f));
    }

    // single gate round: push survivor ids (anchor<<3|class)
    #pragma unroll
    for (int a = 0; a < 4; ++a)
      #pragma unroll
      for (int j = 0; j < 5; ++j)
        if (ff[a * 5 + j] <= thr_inv) {
          int p = atomicAdd(&wcnt, 1);
          if (p < WCAP) u.s.wl[p] = (u32)(((4 * t + a) << 3) | j);
        }
    #pragma unroll
    for (int j = 0; j < 5; ++j)
      if (ff[20 + j] <= thr_inv) {
        int p = atomicAdd(&wcnt, 1);
        if (p < WCAP) u.s.wl[p] = (u32)(((1280 + t) << 3) | j);
      }
    __syncthreads();
    const int wc = wcnt;

    if (wc <= WCAP) {
      // dense exact pass over compacted worklist (~100-400 entries)
      for (int i = t; i < wc; i += NTHR) {
        u32 cd = u.s.wl[i];
        int al = (int)(cd >> 3);
        int jj = (int)(cd & 7u);
        float o   = obj[al];
        float cvv = cls[al * 5 + jj];
        u64 key = score_key(sigmoidf(o), cvv, (off + al) * NUM_CLASSES + jj);
        if (key > thr) { int p = atomicAdd(&cnt, 1); if (p < SCAP) u.s.keys[p] = key; }
      }
    } else {
      // overflow (adversarial only): exact masked-inline for ALL gated
      // entries (worklist discarded; each entry computed once -> exact).
      #pragma unroll
      for (int a = 0; a < 4; ++a)
        #pragma unroll
        for (int j = 0; j < 5; ++j)
          if (ff[a * 5 + j] <= thr_inv) {
            int al = 4 * t + a;
            u64 key = score_key(sigmoidf(obj[al]), cls[al * 5 + j],
                                (off + al) * NUM_CLASSES + j);
            if (key > thr) { int p = atomicAdd(&cnt, 1); if (p < SCAP) u.s.keys[p] = key; }
          }
      #pragma unroll
      for (int j = 0; j < 5; ++j)
        if (ff[20 + j] <= thr_inv) {
          int al = 1280 + t;
          u64 key = score_key(sigmoidf(obj[al]), cls[al * 5 + j],
                              (off + al) * NUM_CLASSES + j);
          if (key > thr) { int p = atomicAdd(&cnt, 1); if (p < SCAP) u.s.keys[p] = key; }
        }
    }
    __syncthreads();
    int cs = cnt; if (cs > SCAP) cs = SCAP;
    __syncthreads();   // uniform snapshot before pad writes

    // final top-64 (cs >= 80 by seed guarantee)
    if (cs > 512) {
      // rare/adversarial fallback: LDS bitonic full sort
      int m = 64; while (m < cs) m <<= 1;
      for (int i = cs + t; i < m; i += NTHR) u.s.keys[i] = 0ull;
      for (int kk = 2; kk <= m; kk <<= 1) {
        for (int j = kk >> 1; j > 0; j >>= 1) {
          __syncthreads();
          for (int i = t; i < m; i += NTHR) {
            int ixj = i ^ j;
            if (ixj > i) {
              u64 a = u.s.keys[i], b = u.s.keys[ixj];
              bool sw = ((i & kk) == 0) ? (a < b) : (a > b);
              if (sw) { u.s.keys[i] = b; u.s.keys[ixj] = a; }
            }
          }
        }
      }
      __syncthreads();
    } else {
      // wave-register tournament: npow<=8 sorted 64-runs, log2 merge rounds
      int npow = 1; while (npow * 64 < cs) npow <<= 1;   // 2,4,8
      for (int i = cs + t; i < npow * 64; i += NTHR) u.s.keys[i] = 0ull;
      __syncthreads();
      for (int r = wv; r < npow; r += 5) {
        u64 v = wave_sort64_desc(u.s.keys[r * 64 + lane], lane);
        u.s.keys[r * 64 + lane] = v;
      }
      __syncthreads();
      for (int half = npow >> 1; half >= 1; half >>= 1) {
        u64 res = 0ull;
        if (wv < half) {
          u64 a    = u.s.keys[(2 * wv) * 64 + lane];
          u64 brev = u.s.keys[(2 * wv + 1) * 64 + 63 - lane];
          res = merge_top64(a, brev, lane);
        }
        __syncthreads();                 // all reads complete
        if (wv < half) u.s.keys[wv * 64 + lane] = res;
        __syncthreads();
      }
    }
    if (t < TOPK) ws_part[(size_t)bx * TOPK + t] = u.s.keys[t];
  }

  // ============== tail election (device-scope message passing) =============
  __syncthreads();                        // drains block's ws_part stores
  if (t == 0) {
    __threadfence();                      // release: stores -> coherence pt
    int old = atomicAdd(&ready[img], 1);  // device-scope by default
    tailflag = (old == NCH - 1);
  }
  __syncthreads();
  if (!tailflag) return;
  __threadfence();                        // acquire: invalidate stale caches

  // ================= merge + NMS phase (tail block only) ===================
  const u64* pbase = ws_part + (size_t)img * NCH * TOPK;

  // round A: 4 waves x top64-of-4-runs covers lvl0's 16 runs; wave4 -> lvl2
  __syncthreads();   // LDS union handoff: scan reads done before m.* writes
  if (wv < 4) {
    const u64* q = pbase + (size_t)(4 * wv) * TOPK;
    u64 a    = q[lane];
    u64 brev = q[64 + 63 - lane];
    u64 c2   = q[128 + lane];
    u64 drev = q[192 + 63 - lane];
    u.m.lds_runs[wv * 64 + lane] = merge4_top64(a, brev, c2, drev, lane);
  } else {
    u.m.lvlkeys[128 + lane] = pbase[20 * TOPK + lane];  // lvl2 final
  }
  __syncthreads();

  // round B: wave0 -> lvl0 final (from LDS), wave1 -> lvl1 final
  if (wv == 0) {
    u64 a    = u.m.lds_runs[lane];
    u64 brev = u.m.lds_runs[64 + 63 - lane];
    u64 c2   = u.m.lds_runs[128 + lane];
    u64 drev = u.m.lds_runs[192 + 63 - lane];
    u.m.lvlkeys[lane] = merge4_top64(a, brev, c2, drev, lane);
  } else if (wv == 1) {
    const u64* q = pbase + (size_t)16 * TOPK;
    u64 a    = q[lane];
    u64 brev = q[64 + 63 - lane];
    u64 c2   = q[128 + lane];
    u64 drev = q[192 + 63 - lane];
    u.m.lvlkeys[64 + lane] = merge4_top64(a, brev, c2, drev, lane);
  }
  __syncthreads();

  // wave0: in-register 192 sort (3 desc runs -> full desc merge).
  // waves 1-3: decode boxes/labels for the 192 entries (one lvl each).
  if (wv == 0) {
    const u64 HIMASK = 0xFFFFFFFF00000000ull;
    u64 s0 = (u.m.lvlkeys[lane] & HIMASK) | (u32)(~(u32)lane);
    int i1 = 64 + 63 - lane;
    u64 s1r = (u.m.lvlkeys[i1] & HIMASK) | (u32)(~(u32)i1);
    int i2 = 128 + 63 - lane;
    u64 s2r = (u.m.lvlkeys[i2] & HIMASK) | (u32)(~(u32)i2);
    u64 hi_ = bmerge64_desc(u64max(s0, s1r), lane);
    u64 lo_ = bmerge64_desc(u64min(s0, s1r), lane);
    u64 R1   = u64max(lo_, s2r);
    u64 out0 = bmerge64_desc(u64max(hi_, R1), lane);
    u64 out1 = bmerge64_desc(u64min(hi_, R1), lane);
    u64 out2 = bmerge64_desc(u64min(lo_, s2r), lane);
    u.m.skeys[lane]       = out0;
    u.m.skeys[64 + lane]  = out1;
    u.m.skeys[128 + lane] = out2;
  } else if (t >= 64 && t < 64 + TOTK) {
    int idx = t - 64;                  // 0..191; lvl = wv-1 (uniform per wave)
    const float* reg; int w; int hw; float stride;
    if (wv == 1)      { reg = reg8;  w = 160; hw = 25600; stride = 8.0f;  }
    else if (wv == 2) { reg = reg16; w = 80;  hw = 6400;  stride = 16.0f; }
    else              { reg = reg32; w = 40;  hw = 1600;  stride = 32.0f; }
    reg += (size_t)img * hw * 4;
    u64 key = u.m.lvlkeys[idx];
    u32 raw = ~((u32)key);
    int a = (int)(raw / NUM_CLASSES);
    int c2 = (int)(raw - (u32)a * NUM_CLASSES);
    int ix = a % w, iy = a / w;
    float ax = __fmul_rn((float)ix + 0.5f, stride);
    float ay = __fmul_rn((float)iy + 0.5f, stride);
    float r0 = reg[a*4+0], r1 = reg[a*4+1], r2 = reg[a*4+2], r3 = reg[a*4+3];
    float cx = __fadd_rn(__fmul_rn(r0, stride), ax);
    float cy = __fadd_rn(__fmul_rn(r1, stride), ay);
    float wd = __fmul_rn(expf(r2), stride);
    float ht = __fmul_rn(expf(r3), stride);
    float x1 = __fsub_rn(cx, __fmul_rn(0.5f, wd));
    float y1 = __fsub_rn(cy, __fmul_rn(0.5f, ht));
    float x2 = __fadd_rn(cx, __fmul_rn(0.5f, wd));
    float y2 = __fadd_rn(cy, __fmul_rn(0.5f, ht));
    u.m.slb[idx] = c2;
    u.m.sbx[idx*4+0] = x1; u.m.sbx[idx*4+1] = y1;
    u.m.sbx[idx*4+2] = x2; u.m.sbx[idx*4+3] = y2;
  }
  __syncthreads();

  // NMS setup: per-thread box (sorted order), global |box| max
  float sc_r = 0.0f, b0 = 0.0f, b1 = 0.0f, b2 = 0.0f, b3 = 0.0f;
  int p = 0, lb_r = 0;
  if (t < TOTK) {
    u64 key = u.m.skeys[t];
    p = (int)(~((u32)key)) & 255;
    sc_r = __uint_as_float((u32)(key >> 32));
    lb_r = u.m.slb[p];
    b0 = u.m.sbx[p*4+0]; b1 = u.m.sbx[p*4+1];
    b2 = u.m.sbx[p*4+2]; b3 = u.m.sbx[p*4+3];
    float lm = fmaxf(fmaxf(fabsf(b0), fabsf(b1)), fmaxf(fabsf(b2), fabsf(b3)));
    #pragma unroll
    for (int d = 32; d > 0; d >>= 1) lm = fmaxf(lm, __shfl_xor(lm, d, 64));
    if (lane == 0) lmarr[wv] = lm;
  }
  __syncthreads();

  const float lmAll = fmaxf(fmaxf(lmarr[0], lmarr[1]), lmarr[2]);
  const float offscale = __fadd_rn(__fmul_rn(2.0f, lmAll), 1.0f);

  float X1 = 0.0f, Y1 = 0.0f, X2 = 0.0f, Y2 = 0.0f, A = 0.0f;
  if (t < TOTK) {
    float off = __fmul_rn((float)lb_r, offscale);
    X1 = __fadd_rn(b0, off); Y1 = __fadd_rn(b1, off);
    X2 = __fadd_rn(b2, off); Y2 = __fadd_rn(b3, off);
    A  = __fmul_rn(__fsub_rn(X2, X1), __fsub_rn(Y2, Y1));
    u.m.sX1[t] = X1; u.m.sY1[t] = Y1; u.m.sX2[t] = X2; u.m.sY2[t] = Y2;
    u.m.sA[t] = A;
    u64 bal = __ballot(sc_r > CONF_THRESH);
    if (lane == 0) svalid[wv] = bal;
  }
  __syncthreads();

  if (t < TOTK) {
    u64 r0m = 0, r1m = 0, r2m = 0;
    for (int j = t + 1; j < TOTK; ++j) {
      float xx1 = fmaxf(X1, u.m.sX1[j]);
      float yy1 = fmaxf(Y1, u.m.sY1[j]);
      float xx2 = fminf(X2, u.m.sX2[j]);
      float yy2 = fminf(Y2, u.m.sY2[j]);
      float wv2 = fmaxf(1e-10f, __fsub_rn(xx2, xx1));
      float hv = fmaxf(1e-10f, __fsub_rn(yy2, yy1));
      float inter = __fmul_rn(wv2, hv);
      float den = __fsub_rn(__fadd_rn(A, u.m.sA[j]), inter);
      float iou = __fdiv_rn(inter, den);
      if (iou > NMS_THRESH) {
        u64 b = 1ull << (j & 63);
        int wd = j >> 6;
        r0m |= (wd == 0) ? b : 0ull;
        r1m |= (wd == 1) ? b : 0ull;
        r2m |= (wd == 2) ? b : 0ull;
      }
    }
    u.m.rows[t*3+0] = r0m; u.m.rows[t*3+1] = r1m; u.m.rows[t*3+2] = r2m;
  }
  __syncthreads();

  if (t < 64) {
    u64 k0 = svalid[0], k1 = svalid[1], k2 = svalid[2];
    #pragma unroll 4
    for (int i = 0; i < 64; ++i) {
      u64 m0 = u.m.rows[i*3+0], m1 = u.m.rows[i*3+1], m2 = u.m.rows[i*3+2];
      u64 sel = 0ull - ((k0 >> i) & 1ull);
      k0 &= ~(m0 & sel); k1 &= ~(m1 & sel); k2 &= ~(m2 & sel);
    }
    #pragma unroll 4
    for (int i = 0; i < 64; ++i) {
      int r = 64 + i;
      u64 m0 = u.m.rows[r*3+0], m1 = u.m.rows[r*3+1], m2 = u.m.rows[r*3+2];
      u64 sel = 0ull - ((k1 >> i) & 1ull);
      k0 &= ~(m0 & sel); k1 &= ~(m1 & sel); k2 &= ~(m2 & sel);
    }
    #pragma unroll 4
    for (int i = 0; i < 64; ++i) {
      int r = 128 + i;
      u64 m0 = u.m.rows[r*3+0], m1 = u.m.rows[r*3+1], m2 = u.m.rows[r*3+2];
      u64 sel = 0ull - ((k2 >> i) & 1ull);
      k0 &= ~(m0 & sel); k1 &= ~(m1 & sel); k2 &= ~(m2 & sel);
    }
    if (t == 0) { skeep[0] = k0; skeep[1] = k1; skeep[2] = k2; }
  }
  __syncthreads();

  if (t < TOTK) {
    float* out_boxes  = out;
    float* out_scores = out + (size_t)BATCH * TOTK * 4;
    float* out_labels = out + (size_t)BATCH * TOTK * 5;
    bool kp = (skeep[t >> 6] >> (t & 63)) & 1ull;
    int gi = img * TOTK + t;
    out_boxes[gi*4+0] = kp ? u.m.sbx[p*4+0] : 0.0f;
    out_boxes[gi*4+1] = kp ? u.m.sbx[p*4+1] : 0.0f;
    out_boxes[gi*4+2] = kp ? u.m.sbx[p*4+2] : 0.0f;
    out_boxes[gi*4+3] = kp ? u.m.sbx[p*4+3] : 0.0f;
    out_scores[gi] = kp ? sc_r : 0.0f;
    out_labels[gi] = kp ? (float)lb_r : -1.0f;
  }
}

extern "C" void kernel_launch(void* const* d_in, const int* in_sizes, int n_in,
                              void* d_out, int out_size, void* d_ws, size_t ws_size,
                              hipStream_t stream) {
  const float* obj8  = (const float*)d_in[0];
  const float* cls8  = (const float*)d_in[1];
  const float* reg8  = (const float*)d_in[2];
  const float* obj16 = (const float*)d_in[3];
  const float* cls16 = (const float*)d_in[4];
  const float* reg16 = (const float*)d_in[5];
  const float* obj32 = (const float*)d_in[6];
  const float* cls32 = (const float*)d_in[7];
  const float* reg32 = (const float*)d_in[8];

  // ws layout: part (2688*64 u64 = 1.376 MB) | ready (128 int)
  u64* ws_part = (u64*)d_ws;
  int* ready   = (int*)((char*)d_ws + (size_t)BATCH * NCH * TOPK * sizeof(u64));

  hipMemsetAsync(ready, 0, BATCH * sizeof(int), stream);
  yolo_fused<<<dim3(BATCH * NCH), dim3(NTHR), 0, stream>>>(
      obj8, cls8, obj16, cls16, obj32, cls32, reg8, reg16, reg32,
      ws_part, ready, (float*)d_out);
}

// Round 7
// 217.426 us; speedup vs baseline: 2.0043x; 2.0043x over previous
//
#include <hip/hip_runtime.h>

// YOLO post-process, 2 kernels (R11 = R9 + scan LDS diet; R10's tail-fusion
// REVERTED):
//  R10 lesson (global): per-block device-scope __threadfence on gfx950
//  (buffer_wbl2/inv, non-coherent per-XCD L2) costs ~100us-scale when issued
//  per block (2688 fences => +218us, VALU 6%, FETCH unchanged). Cross-block
//  handoff must stay at the dispatch boundary; cooperative grid.sync would
//  pay the same per-block fence internally.
//  scan: per (img, 1600-anchor chunk) exact streaming top-64. Float4 loads;
//        fast conservative bound prod=(1+e^-o)(1+e^-c) ~ 1/score^2 gates into
//        a dense LDS worklist; exact OCML score_key on ~100-400 survivors;
//        wave-register tournament top-64.
//        R11: LDS 22.8KB -> 10.3KB (SCAP 1024; u16 worklist, WCAP 1024).
//        R9's occupancy counter (35% ~= 2 blocks/CU) + per-block critical
//        path (~10us) explains 49.5us wall: LDS-pool residency limit.
//        10.3KB => 6 blocks/CU even under a 64KB-pool model.
//        Safety: cnt <= wc (exact pass only pushes gated entries), typical
//        wc 100-400 << 1024; wc>WCAP -> exact masked-inline fallback.
//  merge_nms: one block per image; in-register wave merges of sorted runs
//        (R7: top64(A,B)=max(A[l],B[63-l]) + 6-stage shfl merge).

#define NUM_CLASSES 5
#define CONF_THRESH 0.6f
#define NMS_THRESH  0.2f
#define TOPK   64
#define BATCH  128
#define TOTK   192
#define NCH    21      // per image: 16 (lvl0) + 4 (lvl1) + 1 (lvl2), 1600 anchors each
#define CHUNK  1600
#define SCAP   1024    // LDS candidate buffer (u64); cnt <= wc <= gate count
#define NTHR   320     // 5 waves; anchors: 4/thread vectorized + 1 tail
#define WCAP   1024    // u16 worklist capacity (overflow -> exact fallback)

typedef unsigned long long u64;
typedef unsigned int u32;
typedef unsigned short u16;

// ---------------- shared helpers ----------------

// In-register bitonic sort of 64 u32 across one wave, descending by lane.
__device__ inline u32 wave_sort64_desc_u32(u32 v, int lane) {
  #pragma unroll
  for (int k = 2; k <= 64; k <<= 1) {
    #pragma unroll
    for (int j = k >> 1; j > 0; j >>= 1) {
      u32 o = __shfl_xor(v, j, 64);
      bool keepMax = (((lane & k) == 0) != ((lane & j) != 0));
      v = keepMax ? (v > o ? v : o) : (v < o ? v : o);
    }
  }
  return v;
}

// In-register bitonic sort of 64 u64 across one wave, descending by lane.
__device__ inline u64 wave_sort64_desc(u64 v, int lane) {
  #pragma unroll
  for (int k = 2; k <= 64; k <<= 1) {
    #pragma unroll
    for (int j = k >> 1; j > 0; j >>= 1) {
      u64 o = __shfl_xor(v, j, 64);
      bool keepMax = (((lane & k) == 0) != ((lane & j) != 0));
      v = keepMax ? (v > o ? v : o) : (v < o ? v : o);
    }
  }
  return v;
}

__device__ __forceinline__ u64 u64max(u64 a, u64 b) { return a > b ? a : b; }
__device__ __forceinline__ u64 u64min(u64 a, u64 b) { return a < b ? a : b; }

// Descending bitonic MERGE of a bitonic 64-seq held one elem/lane.
__device__ __forceinline__ u64 bmerge64_desc(u64 v, int lane) {
  #pragma unroll
  for (int j = 32; j > 0; j >>= 1) {
    u64 o = __shfl_xor(v, j, 64);
    v = ((lane & j) == 0) ? u64max(v, o) : u64min(v, o);
  }
  return v;
}

// a = A[lane] (A desc-sorted), brev = B[63-lane] (B desc-sorted).
// Lane-th element of the desc-sorted top-64 of A∪B.
__device__ __forceinline__ u64 merge_top64(u64 a, u64 brev, int lane) {
  return bmerge64_desc(u64max(a, brev), lane);
}

__device__ __forceinline__ u64 merge4_top64(u64 a, u64 brev, u64 c, u64 drev, int lane) {
  u64 ab = merge_top64(a, brev, lane);
  u64 cd = merge_top64(c, drev, lane);
  u64 cdr = __shfl(cd, 63 - lane, 64);
  return merge_top64(ab, cdr, lane);
}

// score = sqrt(sigmoid(obj)*sigmoid(cls)); key = (score_bits<<32) | ~idx
// reproduces lax.top_k order (value desc, index asc). Bit-exact vs numpy
// (absmax 0.0 R2-R10) -- do not alter the float expressions.
__device__ inline u64 score_key(float so, float cv, int idx) {
  float sc = 1.0f / (1.0f + expf(-cv));
  float s  = sqrtf(__fmul_rn(so, sc));
  return ((u64)__float_as_uint(s) << 32) | (u32)(~(u32)idx);
}

__device__ inline float sigmoidf(float x) { return 1.0f / (1.0f + expf(-x)); }

__global__ __launch_bounds__(NTHR) void scan_kernel(
    const float* __restrict__ obj8,  const float* __restrict__ cls8,
    const float* __restrict__ obj16, const float* __restrict__ cls16,
    const float* __restrict__ obj32, const float* __restrict__ cls32,
    u64* __restrict__ ws_part) {
  __shared__ u64 keys[SCAP];
  __shared__ u16 wl[WCAP];
  __shared__ int cnt;
  __shared__ int wcnt;
  __shared__ u32 sthr[5];

  const int bx  = blockIdx.x;
  const int img = bx / NCH;
  const int c   = bx - img * NCH;
  const int t   = threadIdx.x;
  const int lane = t & 63, wv = t >> 6;

  const float *obj, *cls;
  int hw, off;
  if (c < 16)      { obj = obj8;  cls = cls8;  hw = 25600; off = c * CHUNK; }
  else if (c < 20) { obj = obj16; cls = cls16; hw = 6400;  off = (c - 16) * CHUNK; }
  else             { obj = obj32; cls = cls32; hw = 1600;  off = 0; }
  obj += (size_t)img * hw + off;
  cls += ((size_t)img * hw + off) * NUM_CLASSES;

  // ---- cheap bound pass: ff[k] = (1+e^-obj)(1+e^-cls) ~= 1/score^2
  // (monotone DECREASING in score; fast ops, rel err <= ~2^-21).
  // Anchors: thread t owns 4t..4t+3 (float4 loads) + tail 1280+t (scalar).
  // ff[] only indexed by compile-time constants -> stays in VGPRs (R4).
  float ff[25];
  {
    const float4* c4 = (const float4*)cls + (size_t)t * 5;
    float4 q0 = c4[0], q1 = c4[1], q2 = c4[2], q3 = c4[3], q4 = c4[4];
    float4 ov = ((const float4*)obj)[t];
    float cv[20] = { q0.x,q0.y,q0.z,q0.w, q1.x,q1.y,q1.z,q1.w,
                     q2.x,q2.y,q2.z,q2.w, q3.x,q3.y,q3.z,q3.w,
                     q4.x,q4.y,q4.z,q4.w };
    float dob[4] = { 1.0f + __expf(-ov.x), 1.0f + __expf(-ov.y),
                     1.0f + __expf(-ov.z), 1.0f + __expf(-ov.w) };
    #pragma unroll
    for (int a = 0; a < 4; ++a)
      #pragma unroll
      for (int j = 0; j < 5; ++j)
        ff[a * 5 + j] = dob[a] * (1.0f + __expf(-cv[a * 5 + j]));
    float ot = obj[1280 + t];
    float dot_ = 1.0f + __expf(-ot);
    #pragma unroll
    for (int j = 0; j < 5; ++j) {
      float cvt = cls[(1280 + t) * 5 + j];
      ff[20 + j] = dot_ * (1.0f + __expf(-cvt));
    }
  }

  // seed: per-wave 16th-smallest thread-min-prod (= 16th-largest fast score).
  // Every wave's 16th-smallest <= pmax -> >=16 threads per wave (>=80 total)
  // have an entry whose TRUE score >= ts (1e-4 margin >> fast-op err).
  float pmin = ff[0];
  #pragma unroll
  for (int i = 1; i < 25; ++i) pmin = fminf(pmin, ff[i]);
  u32 srt = wave_sort64_desc_u32(__float_as_uint(pmin), lane);
  if (lane == 48) sthr[wv] = srt;        // 16th smallest = 49th largest
  if (t == 0) { cnt = 0; wcnt = 0; }
  __syncthreads();
  u64 thr; float thr_inv;
  {
    float pmax = __uint_as_float(sthr[0]);
    pmax = fmaxf(pmax, __uint_as_float(sthr[1]));
    pmax = fmaxf(pmax, __uint_as_float(sthr[2]));
    pmax = fmaxf(pmax, __uint_as_float(sthr[3]));
    pmax = fmaxf(pmax, __uint_as_float(sthr[4]));
    float ts = sqrtf(__fdiv_rn(1.0f, pmax)) * (1.0f - 1e-4f);
    // key > thr  <=>  score_bits >= bits(ts)  <=>  score >= ts
    thr = ((u64)__float_as_uint(ts) << 32) - 1ull;
    // gate: prod <= thr_inv  <==  score >= ts (2e-4 conservative slack)
    thr_inv = __fdiv_rn(1.0f, __fmul_rn(__fmul_rn(ts, ts), 1.0f - 2e-4f));
  }

  // ---- single gate round: push survivor ids (anchor<<3|class, fits u16) ----
  #pragma unroll
  for (int a = 0; a < 4; ++a)
    #pragma unroll
    for (int j = 0; j < 5; ++j)
      if (ff[a * 5 + j] <= thr_inv) {
        int p = atomicAdd(&wcnt, 1);
        if (p < WCAP) wl[p] = (u16)(((4 * t + a) << 3) | j);
      }
  #pragma unroll
  for (int j = 0; j < 5; ++j)
    if (ff[20 + j] <= thr_inv) {
      int p = atomicAdd(&wcnt, 1);
      if (p < WCAP) wl[p] = (u16)(((1280 + t) << 3) | j);
    }
  __syncthreads();
  const int wc = wcnt;

  if (wc <= WCAP) {
    // dense exact pass over compacted worklist (~100-400 entries; 1 iter)
    for (int i = t; i < wc; i += NTHR) {
      u32 cd = (u32)wl[i];
      int al = (int)(cd >> 3);
      int jj = (int)(cd & 7u);
      float o   = obj[al];
      float cvv = cls[al * 5 + jj];
      u64 key = score_key(sigmoidf(o), cvv, (off + al) * NUM_CLASSES + jj);
      if (key > thr) { int p = atomicAdd(&cnt, 1); if (p < SCAP) keys[p] = key; }
    }
  } else {
    // overflow (adversarial only): exact masked-inline for ALL gated entries
    // (worklist discarded; each gated entry computed exactly once -> exact).
    #pragma unroll
    for (int a = 0; a < 4; ++a)
      #pragma unroll
      for (int j = 0; j < 5; ++j)
        if (ff[a * 5 + j] <= thr_inv) {
          int al = 4 * t + a;
          u64 key = score_key(sigmoidf(obj[al]), cls[al * 5 + j],
                              (off + al) * NUM_CLASSES + j);
          if (key > thr) { int p = atomicAdd(&cnt, 1); if (p < SCAP) keys[p] = key; }
        }
    #pragma unroll
    for (int j = 0; j < 5; ++j)
      if (ff[20 + j] <= thr_inv) {
        int al = 1280 + t;
        u64 key = score_key(sigmoidf(obj[al]), cls[al * 5 + j],
                            (off + al) * NUM_CLASSES + j);
        if (key > thr) { int p = atomicAdd(&cnt, 1); if (p < SCAP) keys[p] = key; }
      }
  }
  __syncthreads();
  int cs = cnt; if (cs > SCAP) cs = SCAP;
  __syncthreads();   // uniform snapshot before pad writes

  // ---- final top-64 (cs >= 80 by seed guarantee) ----
  if (cs > 512) {
    // rare/adversarial fallback: LDS bitonic full sort (m <= SCAP = 1024)
    int m = 64; while (m < cs) m <<= 1;
    for (int i = cs + t; i < m; i += NTHR) keys[i] = 0ull;
    for (int kk = 2; kk <= m; kk <<= 1) {
      for (int j = kk >> 1; j > 0; j >>= 1) {
        __syncthreads();
        for (int i = t; i < m; i += NTHR) {
          int ixj = i ^ j;
          if (ixj > i) {
            u64 a = keys[i], b = keys[ixj];
            bool sw = ((i & kk) == 0) ? (a < b) : (a > b);
            if (sw) { keys[i] = b; keys[ixj] = a; }
          }
        }
      }
    }
    __syncthreads();
  } else {
    // wave-register tournament: npow<=8 sorted 64-runs, log2 merge rounds
    int npow = 1; while (npow * 64 < cs) npow <<= 1;   // 2,4,8
    for (int i = cs + t; i < npow * 64; i += NTHR) keys[i] = 0ull;
    __syncthreads();
    for (int r = wv; r < npow; r += 5) {
      u64 v = wave_sort64_desc(keys[r * 64 + lane], lane);
      keys[r * 64 + lane] = v;
    }
    __syncthreads();
    for (int half = npow >> 1; half >= 1; half >>= 1) {
      u64 res = 0ull;
      if (wv < half) {
        u64 a    = keys[(2 * wv) * 64 + lane];
        u64 brev = keys[(2 * wv + 1) * 64 + 63 - lane];
        res = merge_top64(a, brev, lane);
      }
      __syncthreads();                 // all reads complete
      if (wv < half) keys[wv * 64 + lane] = res;
      __syncthreads();
    }
  }
  if (t < TOPK) ws_part[(size_t)bx * TOPK + t] = keys[t];
}

// One block (256 threads = 4 waves) per image: merge levels + decode + NMS.
__global__ __launch_bounds__(256) void merge_nms_kernel(
    const u64* __restrict__ ws_part,
    const float* __restrict__ reg8, const float* __restrict__ reg16, const float* __restrict__ reg32,
    float* __restrict__ out) {
  __shared__ u64   lds_runs[256];     // round-A lvl0 intermediate runs
  __shared__ u64   lvlkeys[TOTK];     // final per-level top-64 keys (concat order)
  __shared__ u64   skeys[TOTK];       // NMS-sorted keys
  __shared__ int   slb[TOTK];
  __shared__ float sbx[TOTK * 4];
  __shared__ float sX1[TOTK], sY1[TOTK], sX2[TOTK], sY2[TOTK], sA[TOTK];
  __shared__ u64   rows[TOTK * 3];
  __shared__ u64   svalid[3];
  __shared__ u64   skeep[3];
  __shared__ float lmarr[3];

  const int img  = blockIdx.x;
  const int t    = threadIdx.x;
  const int lane = t & 63, wv = t >> 6;

  const u64* pbase = ws_part + (size_t)img * NCH * TOPK;

  // ---- round A: 4 waves x top64-of-4-runs covers lvl0's 16 runs ----
  {
    const u64* q = pbase + (size_t)(4 * wv) * TOPK;
    u64 a    = q[lane];
    u64 brev = q[64 + 63 - lane];
    u64 c    = q[128 + lane];
    u64 drev = q[192 + 63 - lane];
    lds_runs[wv * 64 + lane] = merge4_top64(a, brev, c, drev, lane);
    if (wv == 3) lvlkeys[128 + lane] = pbase[20 * TOPK + lane];  // lvl2 final
  }
  __syncthreads();

  // ---- round B: wave0 -> lvl0 final (from LDS), wave1 -> lvl1 final ----
  if (wv == 0) {
    u64 a    = lds_runs[lane];
    u64 brev = lds_runs[64 + 63 - lane];
    u64 c    = lds_runs[128 + lane];
    u64 drev = lds_runs[192 + 63 - lane];
    lvlkeys[lane] = merge4_top64(a, brev, c, drev, lane);
  } else if (wv == 1) {
    const u64* q = pbase + (size_t)16 * TOPK;
    u64 a    = q[lane];
    u64 brev = q[64 + 63 - lane];
    u64 c    = q[128 + lane];
    u64 drev = q[192 + 63 - lane];
    lvlkeys[64 + lane] = merge4_top64(a, brev, c, drev, lane);
  }
  __syncthreads();

  // ---- wave0: in-register 192 sort (3 desc runs -> full desc merge).
  //      waves 1-3: decode boxes/labels for the 192 entries (one lvl each).
  if (wv == 0) {
    const u64 HIMASK = 0xFFFFFFFF00000000ull;
    u64 s0 = (lvlkeys[lane] & HIMASK) | (u32)(~(u32)lane);
    int i1 = 64 + 63 - lane;
    u64 s1r = (lvlkeys[i1] & HIMASK) | (u32)(~(u32)i1);
    int i2 = 128 + 63 - lane;
    u64 s2r = (lvlkeys[i2] & HIMASK) | (u32)(~(u32)i2);
    u64 hi_ = bmerge64_desc(u64max(s0, s1r), lane);
    u64 lo_ = bmerge64_desc(u64min(s0, s1r), lane);
    u64 R1   = u64max(lo_, s2r);
    u64 out0 = bmerge64_desc(u64max(hi_, R1), lane);
    u64 out1 = bmerge64_desc(u64min(hi_, R1), lane);
    u64 out2 = bmerge64_desc(u64min(lo_, s2r), lane);
    skeys[lane]       = out0;
    skeys[64 + lane]  = out1;
    skeys[128 + lane] = out2;
  } else {
    int idx = t - 64;                  // 0..191; lvl = wv-1 (uniform per wave)
    const float* reg; int w; int hw; float stride;
    if (wv == 1)      { reg = reg8;  w = 160; hw = 25600; stride = 8.0f;  }
    else if (wv == 2) { reg = reg16; w = 80;  hw = 6400;  stride = 16.0f; }
    else              { reg = reg32; w = 40;  hw = 1600;  stride = 32.0f; }
    reg += (size_t)img * hw * 4;
    u64 key = lvlkeys[idx];
    u32 raw = ~((u32)key);
    int a = (int)(raw / NUM_CLASSES);
    int c = (int)(raw - (u32)a * NUM_CLASSES);
    int ix = a % w, iy = a / w;
    float ax = __fmul_rn((float)ix + 0.5f, stride);
    float ay = __fmul_rn((float)iy + 0.5f, stride);
    float r0 = reg[a*4+0], r1 = reg[a*4+1], r2 = reg[a*4+2], r3 = reg[a*4+3];
    float cx = __fadd_rn(__fmul_rn(r0, stride), ax);
    float cy = __fadd_rn(__fmul_rn(r1, stride), ay);
    float wd = __fmul_rn(expf(r2), stride);
    float ht = __fmul_rn(expf(r3), stride);
    float x1 = __fsub_rn(cx, __fmul_rn(0.5f, wd));
    float y1 = __fsub_rn(cy, __fmul_rn(0.5f, ht));
    float x2 = __fadd_rn(cx, __fmul_rn(0.5f, wd));
    float y2 = __fadd_rn(cy, __fmul_rn(0.5f, ht));
    slb[idx] = c;
    sbx[idx*4+0] = x1; sbx[idx*4+1] = y1;
    sbx[idx*4+2] = x2; sbx[idx*4+3] = y2;
  }
  __syncthreads();

  // ---- NMS setup: per-thread box (sorted order), global |box| max ----
  float sc_r = 0.0f, b0 = 0.0f, b1 = 0.0f, b2 = 0.0f, b3 = 0.0f;
  int p = 0, lb_r = 0;
  if (t < TOTK) {
    u64 key = skeys[t];
    p = (int)(~((u32)key)) & 255;
    sc_r = __uint_as_float((u32)(key >> 32));
    lb_r = slb[p];
    b0 = sbx[p*4+0]; b1 = sbx[p*4+1]; b2 = sbx[p*4+2]; b3 = sbx[p*4+3];
    float lm = fmaxf(fmaxf(fabsf(b0), fabsf(b1)), fmaxf(fabsf(b2), fabsf(b3)));
    #pragma unroll
    for (int d = 32; d > 0; d >>= 1) lm = fmaxf(lm, __shfl_xor(lm, d, 64));
    if (lane == 0) lmarr[wv] = lm;
  }
  __syncthreads();

  const float lmAll = fmaxf(fmaxf(lmarr[0], lmarr[1]), lmarr[2]);
  const float offscale = __fadd_rn(__fmul_rn(2.0f, lmAll), 1.0f);

  float X1 = 0.0f, Y1 = 0.0f, X2 = 0.0f, Y2 = 0.0f, A = 0.0f;
  if (t < TOTK) {
    float off = __fmul_rn((float)lb_r, offscale);
    X1 = __fadd_rn(b0, off); Y1 = __fadd_rn(b1, off);
    X2 = __fadd_rn(b2, off); Y2 = __fadd_rn(b3, off);
    A  = __fmul_rn(__fsub_rn(X2, X1), __fsub_rn(Y2, Y1));
    sX1[t] = X1; sY1[t] = Y1; sX2[t] = X2; sY2[t] = Y2; sA[t] = A;
    u64 bal = __ballot(sc_r > CONF_THRESH);
    if (lane == 0) svalid[wv] = bal;
  }
  __syncthreads();

  if (t < TOTK) {
    u64 r0m = 0, r1m = 0, r2m = 0;
    for (int j = t + 1; j < TOTK; ++j) {
      float xx1 = fmaxf(X1, sX1[j]);
      float yy1 = fmaxf(Y1, sY1[j]);
      float xx2 = fminf(X2, sX2[j]);
      float yy2 = fminf(Y2, sY2[j]);
      float wv2 = fmaxf(1e-10f, __fsub_rn(xx2, xx1));
      float hv = fmaxf(1e-10f, __fsub_rn(yy2, yy1));
      float inter = __fmul_rn(wv2, hv);
      float den = __fsub_rn(__fadd_rn(A, sA[j]), inter);
      float iou = __fdiv_rn(inter, den);
      if (iou > NMS_THRESH) {
        u64 b = 1ull << (j & 63);
        int wd = j >> 6;
        r0m |= (wd == 0) ? b : 0ull;
        r1m |= (wd == 1) ? b : 0ull;
        r2m |= (wd == 2) ? b : 0ull;
      }
    }
    rows[t*3+0] = r0m; rows[t*3+1] = r1m; rows[t*3+2] = r2m;
  }
  __syncthreads();

  if (t < 64) {
    u64 k0 = svalid[0], k1 = svalid[1], k2 = svalid[2];
    #pragma unroll 4
    for (int i = 0; i < 64; ++i) {
      u64 m0 = rows[i*3+0], m1 = rows[i*3+1], m2 = rows[i*3+2];
      u64 sel = 0ull - ((k0 >> i) & 1ull);
      k0 &= ~(m0 & sel); k1 &= ~(m1 & sel); k2 &= ~(m2 & sel);
    }
    #pragma unroll 4
    for (int i = 0; i < 64; ++i) {
      int r = 64 + i;
      u64 m0 = rows[r*3+0], m1 = rows[r*3+1], m2 = rows[r*3+2];
      u64 sel = 0ull - ((k1 >> i) & 1ull);
      k0 &= ~(m0 & sel); k1 &= ~(m1 & sel); k2 &= ~(m2 & sel);
    }
    #pragma unroll 4
    for (int i = 0; i < 64; ++i) {
      int r = 128 + i;
      u64 m0 = rows[r*3+0], m1 = rows[r*3+1], m2 = rows[r*3+2];
      u64 sel = 0ull - ((k2 >> i) & 1ull);
      k0 &= ~(m0 & sel); k1 &= ~(m1 & sel); k2 &= ~(m2 & sel);
    }
    if (t == 0) { skeep[0] = k0; skeep[1] = k1; skeep[2] = k2; }
  }
  __syncthreads();

  if (t < TOTK) {
    float* out_boxes  = out;
    float* out_scores = out + (size_t)BATCH * TOTK * 4;
    float* out_labels = out + (size_t)BATCH * TOTK * 5;
    bool kp = (skeep[t >> 6] >> (t & 63)) & 1ull;
    int gi = img * TOTK + t;
    out_boxes[gi*4+0] = kp ? sbx[p*4+0] : 0.0f;
    out_boxes[gi*4+1] = kp ? sbx[p*4+1] : 0.0f;
    out_boxes[gi*4+2] = kp ? sbx[p*4+2] : 0.0f;
    out_boxes[gi*4+3] = kp ? sbx[p*4+3] : 0.0f;
    out_scores[gi] = kp ? sc_r : 0.0f;
    out_labels[gi] = kp ? (float)lb_r : -1.0f;
  }
}

extern "C" void kernel_launch(void* const* d_in, const int* in_sizes, int n_in,
                              void* d_out, int out_size, void* d_ws, size_t ws_size,
                              hipStream_t stream) {
  const float* obj8  = (const float*)d_in[0];
  const float* cls8  = (const float*)d_in[1];
  const float* reg8  = (const float*)d_in[2];
  const float* obj16 = (const float*)d_in[3];
  const float* cls16 = (const float*)d_in[4];
  const float* reg16 = (const float*)d_in[5];
  const float* obj32 = (const float*)d_in[6];
  const float* cls32 = (const float*)d_in[7];
  const float* reg32 = (const float*)d_in[8];

  // ws layout: part (2688*64 u64 = 1.376 MB)
  u64* ws_part = (u64*)d_ws;

  scan_kernel<<<dim3(BATCH * NCH), dim3(NTHR), 0, stream>>>(
      obj8, cls8, obj16, cls16, obj32, cls32, ws_part);
  merge_nms_kernel<<<dim3(BATCH * 3 / 3), dim3(256), 0, stream>>>(
      ws_part, reg8, reg16, reg32, (float*)d_out);
}